// Round 9
// baseline (284.184 us; speedup 1.0000x reference)
//
#include <hip/hip_runtime.h>
#include <hip/hip_bf16.h>

#define T_TOK 2048
#define HID 1024
#define FFNDIM 2048
#define NEXP 8

typedef __attribute__((ext_vector_type(8))) short short8;
typedef __attribute__((ext_vector_type(4))) float f32x4;

__device__ inline unsigned short f2bf(float f) {
  union { float f; unsigned int u; } v; v.f = f;
  unsigned int u = v.u;
  unsigned int r = (u + 0x7fffu + ((u >> 16) & 1u)) >> 16;
  return (unsigned short)r;
}

__device__ inline short8 pack8(float4 a, float4 b) {
  union { __hip_bfloat162 h2[4]; short8 s; } u;
  u.h2[0] = __float22bfloat162_rn(float2{a.x, a.y});
  u.h2[1] = __float22bfloat162_rn(float2{a.z, a.w});
  u.h2[2] = __float22bfloat162_rn(float2{b.x, b.y});
  u.h2[3] = __float22bfloat162_rn(float2{b.z, b.w});
  return u.s;
}

__device__ inline void gload_lds16(const void* g, void* l) {
  __builtin_amdgcn_global_load_lds((const __attribute__((address_space(1))) void*)g,
                                   (__attribute__((address_space(3))) void*)l, 16, 0, 0);
}

// ---------------- router ----------------
__global__ __launch_bounds__(256) void router_kernel(
    const float* __restrict__ x, const float* __restrict__ gw,
    int* __restrict__ counts, int* __restrict__ top_i, float* __restrict__ top_w) {
  int lane = threadIdx.x & 63;
  int t = blockIdx.x * 4 + (threadIdx.x >> 6);
  if (t >= T_TOK) return;
  float xv[16];
#pragma unroll
  for (int i = 0; i < 16; ++i) xv[i] = x[(size_t)t * HID + i * 64 + lane];
  float logit[NEXP];
#pragma unroll
  for (int e = 0; e < NEXP; ++e) {
    float s = 0.f;
#pragma unroll
    for (int i = 0; i < 16; ++i) s += xv[i] * gw[e * HID + i * 64 + lane];
#pragma unroll
    for (int off = 32; off > 0; off >>= 1) s += __shfl_xor(s, off);
    logit[e] = s;
  }
  if (lane == 0) {
    float mx = logit[0];
#pragma unroll
    for (int e = 1; e < NEXP; ++e) mx = fmaxf(mx, logit[e]);
    float p[NEXP]; float sum = 0.f;
#pragma unroll
    for (int e = 0; e < NEXP; ++e) { p[e] = expf(logit[e] - mx); sum += p[e]; }
#pragma unroll
    for (int e = 0; e < NEXP; ++e) p[e] /= sum;
    int i0 = 0;
#pragma unroll
    for (int e = 1; e < NEXP; ++e) if (p[e] > p[i0]) i0 = e;
    int i1 = (i0 == 0) ? 1 : 0;
#pragma unroll
    for (int e = 0; e < NEXP; ++e) if (e != i0 && p[e] > p[i1]) i1 = e;
    float w0 = p[i0], w1v = p[i1];
    float s2 = w0 + w1v;
    w0 /= s2; w1v /= s2;
    top_i[t * 2 + 0] = i0; top_i[t * 2 + 1] = i1;
    top_w[t * 2 + 0] = w0; top_w[t * 2 + 1] = w1v;
    atomicAdd(&counts[i0], 1);
    atomicAdd(&counts[i1], 1);
  }
}

__global__ void offsets_kernel(const int* __restrict__ counts, int* __restrict__ offsets) {
  if (threadIdx.x == 0 && blockIdx.x == 0) {
    int s = 0;
    for (int e = 0; e < NEXP; ++e) { offsets[e] = s; s += counts[e]; }
    offsets[NEXP] = s;
  }
}

__global__ __launch_bounds__(256) void scatter_kernel(
    const int* __restrict__ top_i, const float* __restrict__ top_w,
    const int* __restrict__ offsets, int* __restrict__ cursor,
    int* __restrict__ row_tok, int* __restrict__ tok_rows) {
  int t = blockIdx.x * 256 + threadIdx.x;
  if (t >= T_TOK) return;
#pragma unroll
  for (int k = 0; k < 2; ++k) {
    int e = top_i[t * 2 + k];
    int p = atomicAdd(&cursor[e], 1);
    int idx = offsets[e] + p;
    row_tok[idx] = t;
    tok_rows[t * 2 + k] = idx;
  }
}

__global__ __launch_bounds__(256) void gather_kernel(
    const float* __restrict__ x, const int* __restrict__ row_tok,
    unsigned short* __restrict__ Xg) {
  int r = blockIdx.x;
  int t = row_tok[r];
  int c = threadIdx.x * 4;
  float4 v = *reinterpret_cast<const float4*>(x + (size_t)t * HID + c);
  ushort4 o;
  o.x = f2bf(v.x); o.y = f2bf(v.y); o.z = f2bf(v.z); o.w = f2bf(v.w);
  *reinterpret_cast<ushort4*>(Xg + (size_t)r * HID + c) = o;
}

// ================= GEMM1: 256 tokens x 128 ffn-cols; 8 waves 2Mx4N; BK=64 ========
// A: bf16 Xg via global_load_lds (pre-swizzled source). B: fp32 w1/w3 reg-staged
// (load early / cvt+ds_write late). B tile row r: wn_=r>>6, s=r&63; s<32 -> w1 col
// ntb+wn_*32+s ; s>=32 -> w3 col ntb+wn_*32+(s-32).
__global__ __launch_bounds__(512, 2) void gemm1_f32(
    const unsigned short* __restrict__ Xg,
    const float* __restrict__ w1, const float* __restrict__ w3,
    const int* __restrict__ counts, const int* __restrict__ offsets,
    unsigned short* __restrict__ hbuf) {
  constexpr int BK = 64;
  constexpr int TILE = 256 * BK;
  extern __shared__ unsigned short smem1[];
  unsigned short* sA = smem1;             // [2][256*64]
  unsigned short* sB = smem1 + 2 * TILE;  // [2][256*64]

  int e = blockIdx.z;
  int cnt = counts[e];
  int nt = blockIdx.x, mt = blockIdx.y;
  if (cnt == 0 || mt * 256 >= cnt) return;
  int off = offsets[e];
  int ntb = nt * 128;

  int tid = threadIdx.x, lane = tid & 63, wid = tid >> 6;
  int wm = wid >> 2, wn = wid & 3;
  int fr = lane & 15, fq = lane >> 4;

  // ---- A staging geometry (identical to r8 proven path) ----
  int ri = tid >> 3;                      // row within issue (0..63)
  int g = tid & 7;
  int gsw = (g ^ (ri & 7)) * 8;           // pre-swizzled source granule (elems)
  size_t asrc[4];
  int lbase[4];
#pragma unroll
  for (int j = 0; j < 4; ++j) {
    int r = j * 64 + ri;
    int rg = mt * 256 + r; if (rg > cnt - 1) rg = cnt - 1;
    asrc[j] = (size_t)(off + rg) * HID + gsw;
    lbase[j] = (j * 64 + wid * 8) * BK;
  }
#define ASTAGE(P, K0)                                                       \
  do {                                                                      \
    _Pragma("unroll")                                                       \
    for (int j = 0; j < 4; ++j)                                             \
      gload_lds16(Xg + asrc[j] + (K0), &sA[(P) * TILE + lbase[j]]);         \
  } while (0)

  // ---- B reg-staging geometry: thread -> row rb, half hB (4 granules of 8 fp32) ----
  int rb = tid >> 1;                      // 0..255
  int hB = tid & 1;
  int wn_ = rb >> 6, sB_ = rb & 63;
  const float* bsrcf = ((sB_ < 32) ? w1 : w3) +
      ((size_t)e * FFNDIM + (ntb + wn_ * 32 + (sB_ & 31))) * HID;
  int bdst[4];
#pragma unroll
  for (int gi = 0; gi < 4; ++gi)
    bdst[gi] = rb * BK + (((hB * 4 + gi) ^ (rb & 7)) << 3);

  float4 bp[8];
#define BLOAD(K0)                                                           \
  do {                                                                      \
    _Pragma("unroll")                                                       \
    for (int gi = 0; gi < 4; ++gi) {                                        \
      bp[2 * gi]     = *(const float4*)(bsrcf + (K0) + (hB * 4 + gi) * 8);  \
      bp[2 * gi + 1] = *(const float4*)(bsrcf + (K0) + (hB * 4 + gi) * 8 + 4); \
    }                                                                       \
  } while (0)
#define BWRITE(P)                                                           \
  do {                                                                      \
    _Pragma("unroll")                                                       \
    for (int gi = 0; gi < 4; ++gi)                                          \
      *reinterpret_cast<short8*>(&sB[(P) * TILE + bdst[gi]]) =              \
          pack8(bp[2 * gi], bp[2 * gi + 1]);                                \
  } while (0)

  f32x4 acc[8][4];
#pragma unroll
  for (int mf = 0; mf < 8; ++mf)
#pragma unroll
    for (int nf = 0; nf < 4; ++nf) acc[mf][nf] = (f32x4){0.f, 0.f, 0.f, 0.f};

#define COMP1(P)                                                            \
  do {                                                                      \
    _Pragma("unroll")                                                       \
    for (int kk = 0; kk < 2; ++kk) {                                        \
      short8 bfr[4];                                                        \
      _Pragma("unroll")                                                     \
      for (int nf = 0; nf < 4; ++nf) {                                      \
        int R = wn * 64 + nf * 16 + fr;                                     \
        bfr[nf] = *reinterpret_cast<const short8*>(                         \
            &sB[(P) * TILE + R * BK + (((kk * 4 + fq) ^ (R & 7)) << 3)]);   \
      }                                                                     \
      _Pragma("unroll")                                                     \
      for (int mf = 0; mf < 8; ++mf) {                                      \
        int R = wm * 128 + mf * 16 + fr;                                    \
        short8 afr = *reinterpret_cast<const short8*>(                      \
            &sA[(P) * TILE + R * BK + (((kk * 4 + fq) ^ (R & 7)) << 3)]);   \
        _Pragma("unroll")                                                   \
        for (int nf = 0; nf < 4; ++nf)                                      \
          acc[mf][nf] = __builtin_amdgcn_mfma_f32_16x16x32_bf16(            \
              afr, bfr[nf], acc[mf][nf], 0, 0, 0);                          \
      }                                                                     \
    }                                                                       \
  } while (0)

  const int NT = HID / BK;   // 16
  BLOAD(0);
  ASTAGE(0, 0);
  BWRITE(0);
  __syncthreads();
  int cur = 0;
  for (int t = 0; t < NT; ++t) {
    if (t + 1 < NT) {
      ASTAGE(cur ^ 1, (t + 1) * BK);
      BLOAD((t + 1) * BK);          // fp32 loads in flight across COMP
    }
    COMP1(cur);
    if (t + 1 < NT) BWRITE(cur ^ 1);
    __syncthreads();
    cur ^= 1;
  }

#pragma unroll
  for (int mf = 0; mf < 8; ++mf) {
    int rl = wm * 128 + mf * 16 + fq * 4;
#pragma unroll
    for (int jj = 0; jj < 4; ++jj) {
      int gm = mt * 256 + rl + jj;
      if (gm < cnt) {
#pragma unroll
        for (int nf = 0; nf < 2; ++nf) {
          float h1 = acc[mf][nf][jj];
          float h3 = acc[mf][nf + 2][jj];
          float sv = h1 / (1.f + expf(-h1)) * h3;
          hbuf[(size_t)(off + gm) * FFNDIM + ntb + wn * 32 + nf * 16 + fr] = f2bf(sv);
        }
      }
    }
  }
#undef ASTAGE
#undef BLOAD
#undef BWRITE
#undef COMP1
}

// ================= GEMM2: 256 rows x 128 hid-cols; split-K=2; BK=64 ========
__global__ __launch_bounds__(512, 2) void gemm2_f32(
    const unsigned short* __restrict__ hbuf, const float* __restrict__ w2,
    const int* __restrict__ counts, const int* __restrict__ offsets,
    float* __restrict__ Yg) {
  constexpr int BK = 64;
  constexpr int ATILE = 256 * BK;
  constexpr int BTILE = 128 * BK;
  extern __shared__ unsigned short smem2[];
  unsigned short* sA = smem2;               // [2][256*64]
  unsigned short* sB = smem2 + 2 * ATILE;   // [2][128*64]

  int zz = blockIdx.z;
  int e = zz & 7, kz = zz >> 3;
  int cnt = counts[e];
  int nt = blockIdx.x, mt = blockIdx.y;
  if (cnt == 0 || mt * 256 >= cnt) return;
  int off = offsets[e];
  int ntb = nt * 128;
  int kbase = kz * (FFNDIM / 2);

  int tid = threadIdx.x, lane = tid & 63, wid = tid >> 6;
  int wm = wid >> 2, wn = wid & 3;
  int fr = lane & 15, fq = lane >> 4;

  int ri = tid >> 3;
  int g = tid & 7;
  int gsw = (g ^ (ri & 7)) * 8;
  size_t asrc[4];
  int lbase[4];
#pragma unroll
  for (int j = 0; j < 4; ++j) {
    int r = j * 64 + ri;
    int rg = mt * 256 + r; if (rg > cnt - 1) rg = cnt - 1;
    asrc[j] = (size_t)(off + rg) * FFNDIM + kbase + gsw;
    lbase[j] = (j * 64 + wid * 8) * BK;
  }
#define ASTAGE(P, K0)                                                       \
  do {                                                                      \
    _Pragma("unroll")                                                       \
    for (int j = 0; j < 4; ++j)                                             \
      gload_lds16(hbuf + asrc[j] + (K0), &sA[(P) * ATILE + lbase[j]]);      \
  } while (0)

  // B: 128 rows x 64 K fp32; thread -> row rb=tid>>2, quarter p=tid&3 (2 granules)
  int rb = tid >> 2;
  int p = tid & 3;
  const float* bsrcf = w2 + ((size_t)e * HID + (ntb + rb)) * FFNDIM + kbase;
  int bdst[2];
#pragma unroll
  for (int gi = 0; gi < 2; ++gi)
    bdst[gi] = rb * BK + (((p * 2 + gi) ^ (rb & 7)) << 3);

  float4 bp[4];
#define BLOAD(K0)                                                           \
  do {                                                                      \
    _Pragma("unroll")                                                       \
    for (int gi = 0; gi < 2; ++gi) {                                        \
      bp[2 * gi]     = *(const float4*)(bsrcf + (K0) + (p * 2 + gi) * 8);   \
      bp[2 * gi + 1] = *(const float4*)(bsrcf + (K0) + (p * 2 + gi) * 8 + 4); \
    }                                                                       \
  } while (0)
#define BWRITE(P)                                                           \
  do {                                                                      \
    _Pragma("unroll")                                                       \
    for (int gi = 0; gi < 2; ++gi)                                          \
      *reinterpret_cast<short8*>(&sB[(P) * BTILE + bdst[gi]]) =             \
          pack8(bp[2 * gi], bp[2 * gi + 1]);                                \
  } while (0)

  f32x4 acc[8][2];
#pragma unroll
  for (int mf = 0; mf < 8; ++mf)
#pragma unroll
    for (int nf = 0; nf < 2; ++nf) acc[mf][nf] = (f32x4){0.f, 0.f, 0.f, 0.f};

#define COMP2(P)                                                            \
  do {                                                                      \
    _Pragma("unroll")                                                       \
    for (int kk = 0; kk < 2; ++kk) {                                        \
      short8 bfr[2];                                                        \
      _Pragma("unroll")                                                     \
      for (int nf = 0; nf < 2; ++nf) {                                      \
        int R = wn * 32 + nf * 16 + fr;                                     \
        bfr[nf] = *reinterpret_cast<const short8*>(                         \
            &sB[(P) * BTILE + R * BK + (((kk * 4 + fq) ^ (R & 7)) << 3)]);  \
      }                                                                     \
      _Pragma("unroll")                                                     \
      for (int mf = 0; mf < 8; ++mf) {                                      \
        int R = wm * 128 + mf * 16 + fr;                                    \
        short8 afr = *reinterpret_cast<const short8*>(                      \
            &sA[(P) * ATILE + R * BK + (((kk * 4 + fq) ^ (R & 7)) << 3)]);  \
        _Pragma("unroll")                                                   \
        for (int nf = 0; nf < 2; ++nf)                                      \
          acc[mf][nf] = __builtin_amdgcn_mfma_f32_16x16x32_bf16(            \
              afr, bfr[nf], acc[mf][nf], 0, 0, 0);                          \
      }                                                                     \
    }                                                                       \
  } while (0)

  const int NT = (FFNDIM / 2) / BK;   // 16
  BLOAD(0);
  ASTAGE(0, 0);
  BWRITE(0);
  __syncthreads();
  int cur = 0;
  for (int t = 0; t < NT; ++t) {
    if (t + 1 < NT) {
      ASTAGE(cur ^ 1, (t + 1) * BK);
      BLOAD((t + 1) * BK);
    }
    COMP2(cur);
    if (t + 1 < NT) BWRITE(cur ^ 1);
    __syncthreads();
    cur ^= 1;
  }

  float* yp = Yg + (size_t)kz * (4096 * HID);
#pragma unroll
  for (int mf = 0; mf < 8; ++mf) {
    int rl = wm * 128 + mf * 16 + fq * 4;
#pragma unroll
    for (int jj = 0; jj < 4; ++jj) {
      int gm = mt * 256 + rl + jj;
      if (gm < cnt) {
#pragma unroll
        for (int nf = 0; nf < 2; ++nf)
          yp[(size_t)(off + gm) * HID + ntb + wn * 32 + nf * 16 + fr] = acc[mf][nf][jj];
      }
    }
  }
#undef ASTAGE
#undef BLOAD
#undef BWRITE
#undef COMP2
}

// ======== combine: out[t] = tw0*(Y0[r0]+Y1[r0]) + tw1*(Y0[r1]+Y1[r1]) ========
__global__ __launch_bounds__(256) void combine_kernel(
    const float* __restrict__ Yg, const int* __restrict__ tok_rows,
    const float* __restrict__ top_w, float* __restrict__ out) {
  int t = blockIdx.x;
  int c = threadIdx.x * 4;
  int r0 = tok_rows[t * 2 + 0];
  int r1 = tok_rows[t * 2 + 1];
  float tw0 = top_w[t * 2 + 0];
  float tw1 = top_w[t * 2 + 1];
  const float* Y0 = Yg;
  const float* Y1 = Yg + (size_t)4096 * HID;
  float4 a0 = *reinterpret_cast<const float4*>(Y0 + (size_t)r0 * HID + c);
  float4 b0 = *reinterpret_cast<const float4*>(Y1 + (size_t)r0 * HID + c);
  float4 a1 = *reinterpret_cast<const float4*>(Y0 + (size_t)r1 * HID + c);
  float4 b1 = *reinterpret_cast<const float4*>(Y1 + (size_t)r1 * HID + c);
  float4 o;
  o.x = tw0 * (a0.x + b0.x) + tw1 * (a1.x + b1.x);
  o.y = tw0 * (a0.y + b0.y) + tw1 * (a1.y + b1.y);
  o.z = tw0 * (a0.z + b0.z) + tw1 * (a1.z + b1.z);
  o.w = tw0 * (a0.w + b0.w) + tw1 * (a1.w + b1.w);
  *reinterpret_cast<float4*>(out + (size_t)t * HID + c) = o;
}

extern "C" void kernel_launch(void* const* d_in, const int* in_sizes, int n_in,
                              void* d_out, int out_size, void* d_ws, size_t ws_size,
                              hipStream_t stream) {
  const float* x  = (const float*)d_in[0];
  const float* gw = (const float*)d_in[1];
  const float* w1 = (const float*)d_in[2];
  const float* w3 = (const float*)d_in[3];
  const float* w2 = (const float*)d_in[4];
  float* out = (float*)d_out;

  char* ws = (char*)d_ws;
  int*   counts   = (int*)(ws + 0);
  int*   cursor   = (int*)(ws + 32);
  int*   offsets  = (int*)(ws + 64);
  int*   top_i    = (int*)(ws + 1024);
  float* top_w    = (float*)(ws + 17408);
  int*   row_tok  = (int*)(ws + 33792);
  int*   tok_rows = (int*)(ws + 50176);
  unsigned short* Xg   = (unsigned short*)(ws + 66560);     // 4224*1024 bf16
  unsigned short* hbuf = (unsigned short*)(ws + 8717312);   // 4224*2048 bf16
  float*          Yg   = (float*)(ws + 26018816);           // 2 planes * 4096*1024 f32

  hipFuncSetAttribute((const void*)gemm1_f32,
                      hipFuncAttributeMaxDynamicSharedMemorySize, 131072);
  hipFuncSetAttribute((const void*)gemm2_f32,
                      hipFuncAttributeMaxDynamicSharedMemorySize, 98304);

  hipMemsetAsync(ws, 0, 128, stream);

  router_kernel<<<T_TOK / 4, 256, 0, stream>>>(x, gw, counts, top_i, top_w);
  offsets_kernel<<<1, 64, 0, stream>>>(counts, offsets);
  scatter_kernel<<<(T_TOK + 255) / 256, 256, 0, stream>>>(top_i, top_w, offsets, cursor, row_tok, tok_rows);
  gather_kernel<<<T_TOK * 2, 256, 0, stream>>>(x, row_tok, Xg);

  gemm1_f32<<<dim3(16, 8, NEXP), 512, 131072, stream>>>(Xg, w1, w3, counts, offsets, hbuf);
  gemm2_f32<<<dim3(8, 8, NEXP * 2), 512, 98304, stream>>>(hbuf, w2, counts, offsets, Yg);
  combine_kernel<<<T_TOK, 256, 0, stream>>>(Yg, tok_rows, top_w, out);
}

// Round 10
// 240.715 us; speedup vs baseline: 1.1806x; 1.1806x over previous
//
#include <hip/hip_runtime.h>
#include <hip/hip_bf16.h>

#define T_TOK 2048
#define HID 1024
#define FFNDIM 2048
#define NEXP 8

typedef __attribute__((ext_vector_type(8))) short short8;
typedef __attribute__((ext_vector_type(4))) float f32x4;

__device__ inline unsigned short f2bf(float f) {
  union { float f; unsigned int u; } v; v.f = f;
  unsigned int u = v.u;
  unsigned int r = (u + 0x7fffu + ((u >> 16) & 1u)) >> 16;
  return (unsigned short)r;
}

__device__ inline short8 pack8(float4 a, float4 b) {
  union { __hip_bfloat162 h2[4]; short8 s; } u;
  u.h2[0] = __float22bfloat162_rn(float2{a.x, a.y});
  u.h2[1] = __float22bfloat162_rn(float2{a.z, a.w});
  u.h2[2] = __float22bfloat162_rn(float2{b.x, b.y});
  u.h2[3] = __float22bfloat162_rn(float2{b.z, b.w});
  return u.s;
}

__device__ inline void gload_lds16(const void* g, void* l) {
  __builtin_amdgcn_global_load_lds((const __attribute__((address_space(1))) void*)g,
                                   (__attribute__((address_space(3))) void*)l, 16, 0, 0);
}

// ---------------- router ----------------
__global__ __launch_bounds__(256) void router_kernel(
    const float* __restrict__ x, const float* __restrict__ gw,
    int* __restrict__ counts, int* __restrict__ top_i, float* __restrict__ top_w) {
  int lane = threadIdx.x & 63;
  int t = blockIdx.x * 4 + (threadIdx.x >> 6);
  if (t >= T_TOK) return;
  float xv[16];
#pragma unroll
  for (int i = 0; i < 16; ++i) xv[i] = x[(size_t)t * HID + i * 64 + lane];
  float logit[NEXP];
#pragma unroll
  for (int e = 0; e < NEXP; ++e) {
    float s = 0.f;
#pragma unroll
    for (int i = 0; i < 16; ++i) s += xv[i] * gw[e * HID + i * 64 + lane];
#pragma unroll
    for (int off = 32; off > 0; off >>= 1) s += __shfl_xor(s, off);
    logit[e] = s;
  }
  if (lane == 0) {
    float mx = logit[0];
#pragma unroll
    for (int e = 1; e < NEXP; ++e) mx = fmaxf(mx, logit[e]);
    float p[NEXP]; float sum = 0.f;
#pragma unroll
    for (int e = 0; e < NEXP; ++e) { p[e] = expf(logit[e] - mx); sum += p[e]; }
#pragma unroll
    for (int e = 0; e < NEXP; ++e) p[e] /= sum;
    int i0 = 0;
#pragma unroll
    for (int e = 1; e < NEXP; ++e) if (p[e] > p[i0]) i0 = e;
    int i1 = (i0 == 0) ? 1 : 0;
#pragma unroll
    for (int e = 0; e < NEXP; ++e) if (e != i0 && p[e] > p[i1]) i1 = e;
    float w0 = p[i0], w1v = p[i1];
    float s2 = w0 + w1v;
    w0 /= s2; w1v /= s2;
    top_i[t * 2 + 0] = i0; top_i[t * 2 + 1] = i1;
    top_w[t * 2 + 0] = w0; top_w[t * 2 + 1] = w1v;
    atomicAdd(&counts[i0], 1);
    atomicAdd(&counts[i1], 1);
  }
}

__global__ void offsets_kernel(const int* __restrict__ counts, int* __restrict__ offsets) {
  if (threadIdx.x == 0 && blockIdx.x == 0) {
    int s = 0;
    for (int e = 0; e < NEXP; ++e) { offsets[e] = s; s += counts[e]; }
    offsets[NEXP] = s;
  }
}

__global__ __launch_bounds__(256) void scatter_kernel(
    const int* __restrict__ top_i, const float* __restrict__ top_w,
    const int* __restrict__ offsets, int* __restrict__ cursor,
    int* __restrict__ row_tok, int* __restrict__ tok_rows) {
  int t = blockIdx.x * 256 + threadIdx.x;
  if (t >= T_TOK) return;
#pragma unroll
  for (int k = 0; k < 2; ++k) {
    int e = top_i[t * 2 + k];
    int p = atomicAdd(&cursor[e], 1);
    int idx = offsets[e] + p;
    row_tok[idx] = t;
    tok_rows[t * 2 + k] = idx;
  }
}

__global__ __launch_bounds__(256) void gather_kernel(
    const float* __restrict__ x, const int* __restrict__ row_tok,
    unsigned short* __restrict__ Xg) {
  int r = blockIdx.x;
  int t = row_tok[r];
  int c = threadIdx.x * 4;
  float4 v = *reinterpret_cast<const float4*>(x + (size_t)t * HID + c);
  ushort4 o;
  o.x = f2bf(v.x); o.y = f2bf(v.y); o.z = f2bf(v.z); o.w = f2bf(v.w);
  *reinterpret_cast<ushort4*>(Xg + (size_t)r * HID + c) = o;
}

// ======== GEMM1: 128 tokens x 64 ffn-cols x {w1,w3}; 4 waves 2x2; BK=32 ========
// A: bf16 Xg via DMA (2-bit granule swizzle). B: fp32 w1/w3 via DMA into fp32 LDS
// tile (3-bit granule swizzle on 128B rows); cvt to bf16 at fragment-read time.
// B tile row r: wn_=r>>6, s=r&63; s<32 -> w1 col ntb+wn_*32+s ; else w3 col
// ntb+wn_*32+(s-32). Wave (wm,wn): tokens wm*64+mf*16.., B rows wn*64+nf*16+fr.
__global__ __launch_bounds__(256) void gemm1_d(
    const unsigned short* __restrict__ Xg,
    const float* __restrict__ w1, const float* __restrict__ w3,
    const int* __restrict__ counts, const int* __restrict__ offsets,
    unsigned short* __restrict__ hbuf) {
  __shared__ alignas(16) unsigned short sA[2][128 * 32];  // 16 KB
  __shared__ alignas(16) float sBf[2][128 * 32];          // 32 KB

  int e = blockIdx.z;
  int cnt = counts[e];
  int nt = blockIdx.x, mt = blockIdx.y;
  if (cnt == 0 || mt * 128 >= cnt) return;
  int off = offsets[e];
  int ntb = nt * 64;

  int tid = threadIdx.x, lane = tid & 63, wid = tid >> 6;
  int wm = wid >> 1, wn = wid & 1;
  int fr = lane & 15, fq = lane >> 4;

  // ---- A staging: 2 sets of 4KB; set s covers rows s*64 + (tid>>2) ----
  size_t asrc[2]; int albase[2];
#pragma unroll
  for (int s = 0; s < 2; ++s) {
    int idx = s * 256 + tid;
    int row = idx >> 2, g = idx & 3;
    int rg = mt * 128 + row; if (rg > cnt - 1) rg = cnt - 1;
    asrc[s] = (size_t)(off + rg) * HID + ((g ^ (row & 3)) << 3);
    albase[s] = (s * 256 + wid * 64) * 8;   // shorts
  }
  // ---- B staging: 4 sets of 4KB; set s covers rows s*32 + (tid>>3) ----
  const float* bptr[4]; int blbase[4];
#pragma unroll
  for (int s = 0; s < 4; ++s) {
    int idx = s * 256 + tid;
    int row = idx >> 3, g = idx & 7;
    int wn_ = row >> 6, ss = row & 63;
    const float* mat = (ss < 32) ? w1 : w3;
    bptr[s] = mat + ((size_t)e * FFNDIM + (ntb + wn_ * 32 + (ss & 31))) * HID
                  + ((g ^ (row & 7)) << 2);
    blbase[s] = (s * 256 + wid * 64) * 4;   // floats
  }

#define STAGE1(P, K0)                                                       \
  do {                                                                      \
    _Pragma("unroll")                                                       \
    for (int s = 0; s < 2; ++s)                                             \
      gload_lds16(Xg + asrc[s] + (K0), &sA[P][albase[s]]);                  \
    _Pragma("unroll")                                                       \
    for (int s = 0; s < 4; ++s)                                             \
      gload_lds16(bptr[s] + (K0), &sBf[P][blbase[s]]);                      \
  } while (0)

  f32x4 acc[4][4];
#pragma unroll
  for (int mf = 0; mf < 4; ++mf)
#pragma unroll
    for (int nf = 0; nf < 4; ++nf) acc[mf][nf] = (f32x4){0.f, 0.f, 0.f, 0.f};

#define COMP1(P)                                                            \
  do {                                                                      \
    short8 bfr[4];                                                          \
    _Pragma("unroll")                                                       \
    for (int nf = 0; nf < 4; ++nf) {                                        \
      int R = wn * 64 + nf * 16 + fr;                                       \
      float4 c0 = *reinterpret_cast<const float4*>(                         \
          &sBf[P][R * 32 + (((2 * fq) ^ (R & 7)) << 2)]);                   \
      float4 c1 = *reinterpret_cast<const float4*>(                         \
          &sBf[P][R * 32 + (((2 * fq + 1) ^ (R & 7)) << 2)]);               \
      bfr[nf] = pack8(c0, c1);                                              \
    }                                                                       \
    __builtin_amdgcn_s_setprio(1);                                          \
    _Pragma("unroll")                                                       \
    for (int mf = 0; mf < 4; ++mf) {                                        \
      int Ra = wm * 64 + mf * 16 + fr;                                      \
      short8 afr = *reinterpret_cast<const short8*>(                        \
          &sA[P][Ra * 32 + ((fq ^ (Ra & 3)) << 3)]);                        \
      _Pragma("unroll")                                                     \
      for (int nf = 0; nf < 4; ++nf)                                        \
        acc[mf][nf] = __builtin_amdgcn_mfma_f32_16x16x32_bf16(              \
            afr, bfr[nf], acc[mf][nf], 0, 0, 0);                            \
    }                                                                       \
    __builtin_amdgcn_s_setprio(0);                                          \
  } while (0)

  const int NT = HID / 32;   // 32
  STAGE1(0, 0);
  __syncthreads();
  int cur = 0;
  for (int t = 0; t < NT; ++t) {
    if (t + 1 < NT) STAGE1(cur ^ 1, (t + 1) * 32);
    COMP1(cur);
    __syncthreads();
    cur ^= 1;
  }

#pragma unroll
  for (int mf = 0; mf < 4; ++mf) {
    int rl = wm * 64 + mf * 16 + fq * 4;
#pragma unroll
    for (int jj = 0; jj < 4; ++jj) {
      int gm = mt * 128 + rl + jj;
      if (gm < cnt) {
#pragma unroll
        for (int nf = 0; nf < 2; ++nf) {
          float h1 = acc[mf][nf][jj];
          float h3 = acc[mf][nf + 2][jj];
          float sv = h1 / (1.f + expf(-h1)) * h3;
          hbuf[(size_t)(off + gm) * FFNDIM + ntb + wn * 32 + nf * 16 + fr] = f2bf(sv);
        }
      }
    }
  }
#undef STAGE1
#undef COMP1
}

// ======== GEMM2: 128 rows x 128 hid-cols; 4 waves 2x2; BK=32; split-K=2 ========
__global__ __launch_bounds__(256) void gemm2_d(
    const unsigned short* __restrict__ hbuf, const float* __restrict__ w2,
    const int* __restrict__ counts, const int* __restrict__ offsets,
    float* __restrict__ Yg) {
  __shared__ alignas(16) unsigned short sA[2][128 * 32];  // 16 KB
  __shared__ alignas(16) float sBf[2][128 * 32];          // 32 KB

  int zz = blockIdx.z;
  int e = zz & 7, kz = zz >> 3;
  int cnt = counts[e];
  int nt = blockIdx.x, mt = blockIdx.y;
  if (cnt == 0 || mt * 128 >= cnt) return;
  int off = offsets[e];
  int ntb = nt * 128;
  int kbase = kz * (FFNDIM / 2);

  int tid = threadIdx.x, lane = tid & 63, wid = tid >> 6;
  int wm = wid >> 1, wn = wid & 1;
  int fr = lane & 15, fq = lane >> 4;

  size_t asrc[2]; int albase[2];
#pragma unroll
  for (int s = 0; s < 2; ++s) {
    int idx = s * 256 + tid;
    int row = idx >> 2, g = idx & 3;
    int rg = mt * 128 + row; if (rg > cnt - 1) rg = cnt - 1;
    asrc[s] = (size_t)(off + rg) * FFNDIM + kbase + ((g ^ (row & 3)) << 3);
    albase[s] = (s * 256 + wid * 64) * 8;
  }
  const float* bptr[4]; int blbase[4];
#pragma unroll
  for (int s = 0; s < 4; ++s) {
    int idx = s * 256 + tid;
    int row = idx >> 3, g = idx & 7;
    bptr[s] = w2 + ((size_t)e * HID + (ntb + row)) * FFNDIM + kbase
                 + ((g ^ (row & 7)) << 2);
    blbase[s] = (s * 256 + wid * 64) * 4;
  }

#define STAGE2(P, K0)                                                       \
  do {                                                                      \
    _Pragma("unroll")                                                       \
    for (int s = 0; s < 2; ++s)                                             \
      gload_lds16(hbuf + asrc[s] + (K0), &sA[P][albase[s]]);                \
    _Pragma("unroll")                                                       \
    for (int s = 0; s < 4; ++s)                                             \
      gload_lds16(bptr[s] + (K0), &sBf[P][blbase[s]]);                      \
  } while (0)

  f32x4 acc[4][4];
#pragma unroll
  for (int mf = 0; mf < 4; ++mf)
#pragma unroll
    for (int nf = 0; nf < 4; ++nf) acc[mf][nf] = (f32x4){0.f, 0.f, 0.f, 0.f};

#define COMP2(P)                                                            \
  do {                                                                      \
    short8 bfr[4];                                                          \
    _Pragma("unroll")                                                       \
    for (int nf = 0; nf < 4; ++nf) {                                        \
      int R = wn * 64 + nf * 16 + fr;                                       \
      float4 c0 = *reinterpret_cast<const float4*>(                         \
          &sBf[P][R * 32 + (((2 * fq) ^ (R & 7)) << 2)]);                   \
      float4 c1 = *reinterpret_cast<const float4*>(                         \
          &sBf[P][R * 32 + (((2 * fq + 1) ^ (R & 7)) << 2)]);               \
      bfr[nf] = pack8(c0, c1);                                              \
    }                                                                       \
    __builtin_amdgcn_s_setprio(1);                                          \
    _Pragma("unroll")                                                       \
    for (int mf = 0; mf < 4; ++mf) {                                        \
      int Ra = wm * 64 + mf * 16 + fr;                                      \
      short8 afr = *reinterpret_cast<const short8*>(                        \
          &sA[P][Ra * 32 + ((fq ^ (Ra & 3)) << 3)]);                        \
      _Pragma("unroll")                                                     \
      for (int nf = 0; nf < 4; ++nf)                                        \
        acc[mf][nf] = __builtin_amdgcn_mfma_f32_16x16x32_bf16(              \
            afr, bfr[nf], acc[mf][nf], 0, 0, 0);                            \
    }                                                                       \
    __builtin_amdgcn_s_setprio(0);                                          \
  } while (0)

  const int NT = (FFNDIM / 2) / 32;   // 32
  STAGE2(0, 0);
  __syncthreads();
  int cur = 0;
  for (int t = 0; t < NT; ++t) {
    if (t + 1 < NT) STAGE2(cur ^ 1, (t + 1) * 32);
    COMP2(cur);
    __syncthreads();
    cur ^= 1;
  }

  float* yp = Yg + (size_t)kz * (4096 * HID);
#pragma unroll
  for (int mf = 0; mf < 4; ++mf) {
    int rl = wm * 64 + mf * 16 + fq * 4;
#pragma unroll
    for (int jj = 0; jj < 4; ++jj) {
      int gm = mt * 128 + rl + jj;
      if (gm < cnt) {
#pragma unroll
        for (int nf = 0; nf < 4; ++nf)
          yp[(size_t)(off + gm) * HID + ntb + wn * 64 + nf * 16 + fr] = acc[mf][nf][jj];
      }
    }
  }
#undef STAGE2
#undef COMP2
}

// ======== combine: out[t] = tw0*(Y0[r0]+Y1[r0]) + tw1*(Y0[r1]+Y1[r1]) ========
__global__ __launch_bounds__(256) void combine_kernel(
    const float* __restrict__ Yg, const int* __restrict__ tok_rows,
    const float* __restrict__ top_w, float* __restrict__ out) {
  int t = blockIdx.x;
  int c = threadIdx.x * 4;
  int r0 = tok_rows[t * 2 + 0];
  int r1 = tok_rows[t * 2 + 1];
  float tw0 = top_w[t * 2 + 0];
  float tw1 = top_w[t * 2 + 1];
  const float* Y0 = Yg;
  const float* Y1 = Yg + (size_t)4096 * HID;
  float4 a0 = *reinterpret_cast<const float4*>(Y0 + (size_t)r0 * HID + c);
  float4 b0 = *reinterpret_cast<const float4*>(Y1 + (size_t)r0 * HID + c);
  float4 a1 = *reinterpret_cast<const float4*>(Y0 + (size_t)r1 * HID + c);
  float4 b1 = *reinterpret_cast<const float4*>(Y1 + (size_t)r1 * HID + c);
  float4 o;
  o.x = tw0 * (a0.x + b0.x) + tw1 * (a1.x + b1.x);
  o.y = tw0 * (a0.y + b0.y) + tw1 * (a1.y + b1.y);
  o.z = tw0 * (a0.z + b0.z) + tw1 * (a1.z + b1.z);
  o.w = tw0 * (a0.w + b0.w) + tw1 * (a1.w + b1.w);
  *reinterpret_cast<float4*>(out + (size_t)t * HID + c) = o;
}

extern "C" void kernel_launch(void* const* d_in, const int* in_sizes, int n_in,
                              void* d_out, int out_size, void* d_ws, size_t ws_size,
                              hipStream_t stream) {
  const float* x  = (const float*)d_in[0];
  const float* gw = (const float*)d_in[1];
  const float* w1 = (const float*)d_in[2];
  const float* w3 = (const float*)d_in[3];
  const float* w2 = (const float*)d_in[4];
  float* out = (float*)d_out;

  char* ws = (char*)d_ws;
  int*   counts   = (int*)(ws + 0);
  int*   cursor   = (int*)(ws + 32);
  int*   offsets  = (int*)(ws + 64);
  int*   top_i    = (int*)(ws + 1024);
  float* top_w    = (float*)(ws + 17408);
  int*   row_tok  = (int*)(ws + 33792);
  int*   tok_rows = (int*)(ws + 50176);
  unsigned short* Xg   = (unsigned short*)(ws + 66560);     // 4224*1024 bf16
  unsigned short* hbuf = (unsigned short*)(ws + 8717312);   // 4224*2048 bf16
  float*          Yg   = (float*)(ws + 26018816);           // 2 planes * 4096*1024 f32

  hipMemsetAsync(ws, 0, 128, stream);

  router_kernel<<<T_TOK / 4, 256, 0, stream>>>(x, gw, counts, top_i, top_w);
  offsets_kernel<<<1, 64, 0, stream>>>(counts, offsets);
  scatter_kernel<<<(T_TOK + 255) / 256, 256, 0, stream>>>(top_i, top_w, offsets, cursor, row_tok, tok_rows);
  gather_kernel<<<T_TOK * 2, 256, 0, stream>>>(x, row_tok, Xg);

  // gemm1: 32 n-tiles (64 ffn-cols x {w1,w3}), mt up to 16, 8 experts -> up to 1024 active
  gemm1_d<<<dim3(FFNDIM / 64, 16, NEXP), 256, 0, stream>>>(Xg, w1, w3, counts, offsets, hbuf);
  // gemm2: 8 n-tiles (128 hid-cols), mt up to 16, 8 experts x splitK=2 -> up to 512 active
  gemm2_d<<<dim3(HID / 128, 16, NEXP * 2), 256, 0, stream>>>(hbuf, w2, counts, offsets, Yg);
  combine_kernel<<<T_TOK, 256, 0, stream>>>(Yg, tok_rows, top_w, out);
}